// Round 7
// baseline (109.171 us; speedup 1.0000x reference)
//
#include <hip/hip_runtime.h>
#include <math.h>

// LRPCHead: C=512, H=W=160 (HW=25600), NC=1203, LC=64
// Outputs (flat, fp32): loc_out [64*25600] | cls_out [1203*25600] | mask [25600]

constexpr int C_   = 512;
constexpr int HW_  = 25600;
constexpr int NC_  = 1203;

constexpr int LOC_OFF_  = 0;
constexpr int CLS_OFF_  = 64 * HW_;              // 1,638,400
constexpr int MASK_OFF_ = CLS_OFF_ + NC_ * HW_;  // 32,435,200

constexpr int PF_BLOCKS_   = HW_ / 64;   // 400
constexpr int LOC_BLOCKS_  = 400;        // 100 hw-tiles x 4 channel-tiles
constexpr int FILL_BLOCKS_ = 2048;

typedef float vfloat4 __attribute__((ext_vector_type(4)));

// ---------------------------------------------------------------- init
__global__ void k_init(int* cnt) { *cnt = 0; }

// ---------------- fused: pf mask+compact | loc conv | cls bias fill
// (verbatim round-5 bodies; NO gather here — that stays a separate kernel)
__global__ __launch_bounds__(256) void k_main(
    const float* __restrict__ cls_feat, const float* __restrict__ loc_feat,
    const float* __restrict__ conf, const float* __restrict__ pf_w,
    const float* __restrict__ pf_b, const float* __restrict__ vocab_b,
    const float* __restrict__ loc_w, const float* __restrict__ loc_b,
    float* __restrict__ out, int* __restrict__ cnt,
    int* __restrict__ idxList)
{
    const int bid = blockIdx.x;
    const int tid = threadIdx.x;

    if (bid < PF_BLOCKS_) {
        // ---------------- pf score + mask + compact (round-5 k_pf_mask body)
        __shared__ double sPart[256];
        const int hwi   = tid & 63;
        const int slice = tid >> 6;
        const int hw    = bid * 64 + hwi;
        const float* p  = cls_feat + (size_t)slice * 128 * HW_ + hw;
        const float* w  = pf_w + slice * 128;
        double acc = 0.0;
        #pragma unroll 4
        for (int k = 0; k < 128; ++k)
            acc += (double)w[k] * (double)p[(size_t)k * HW_];
        sPart[tid] = acc;
        __syncthreads();
        if (slice == 0) {
            double s = sPart[hwi] + sPart[64 + hwi] + sPart[128 + hwi] +
                       sPart[192 + hwi] + (double)pf_b[0];
            double sig = 1.0 / (1.0 + exp(-s));
            bool m = sig > (double)conf[0];
            out[MASK_OFF_ + hw] = m ? 1.0f : 0.0f;
            if (m) {
                int pos = atomicAdd(cnt, 1);
                if (pos < HW_) idxList[pos] = hw;
            }
        }
    } else if (bid < PF_BLOCKS_ + LOC_BLOCKS_) {
        // ---------------- loc 1x1 conv (round-5 k_loc body)
        const int j   = bid - PF_BLOCKS_;
        const int hwb = j % 100;
        const int o0  = (j / 100) * 16;
        __shared__ float sw[16][64];
        for (int i = tid; i < 16 * 64; i += 256)
            sw[i >> 6][i & 63] = loc_w[(o0 + (i >> 6)) * 64 + (i & 63)];
        __syncthreads();
        const int hw = hwb * 256 + tid;
        float acc[16];
        #pragma unroll
        for (int r = 0; r < 16; ++r) acc[r] = loc_b[o0 + r];
        for (int i = 0; i < 64; ++i) {
            float f = loc_feat[(size_t)i * HW_ + hw];
            #pragma unroll
            for (int r = 0; r < 16; ++r) acc[r] += sw[r][i] * f;
        }
        #pragma unroll
        for (int r = 0; r < 16; ++r)
            out[LOC_OFF_ + (size_t)(o0 + r) * HW_ + hw] = acc[r];
    } else {
        // ---------------- fill cls_out with vocab_b (round-5 k_fill_cls body)
        const int fb = bid - PF_BLOCKS_ - LOC_BLOCKS_;
        const int total4 = NC_ * HW_ / 4;  // 7,699,200 float4s
        vfloat4* o = (vfloat4*)(out + CLS_OFF_);
        for (int i = fb * 256 + tid; i < total4; i += FILL_BLOCKS_ * 256) {
            int v = i / (HW_ / 4);
            float b = vocab_b[v];
            vfloat4 val = {b, b, b, b};
            __builtin_nontemporal_store(val, &o[i]);
        }
    }
}

// ------------- gather live columns TRANSPOSED: BdT_T[k][j], stride jcap
// (verbatim round-5 k_gatherT)
__global__ __launch_bounds__(256) void k_gatherT(
    const float* __restrict__ cls_feat, const int* __restrict__ cnt,
    const int* __restrict__ idxList, float* __restrict__ BdT_T, int jcap)
{
    const int count = min(*cnt, HW_);
    if (count > jcap) return;  // fallback path will handle
    const int t = threadIdx.x;
    for (int j = blockIdx.x; j < count; j += gridDim.x) {
        const int hw = idxList[j];
        BdT_T[(size_t)t * jcap + j]         = cls_feat[(size_t)t * HW_ + hw];
        BdT_T[(size_t)(256 + t) * jcap + j] = cls_feat[(size_t)(256 + t) * HW_ + hw];
    }
}

// ------------- dense GEMM: 8 v-rows per wave (uniform A), lane->j (coalesced B)
// block = 4 waves = 32 v rows; grid (ceil(NC/32), jcap/64)
__global__ __launch_bounds__(256) void k_gemm2(
    const float* __restrict__ vocab_w, const float* __restrict__ vocab_b,
    const int* __restrict__ cnt, const int* __restrict__ idxList,
    const float* __restrict__ BdT_T, float* __restrict__ out, int jcap)
{
    const int count = min(*cnt, HW_);
    if (count == 0 || count > jcap) return;
    const int j0 = blockIdx.y * 64;
    if (j0 >= count) return;

    const int wv = __builtin_amdgcn_readfirstlane((int)threadIdx.x >> 6);
    const int v0 = (blockIdx.x * 4 + wv) * 8;
    if (v0 >= NC_) return;
    const int lane = threadIdx.x & 63;
    const int j    = j0 + lane;
    const bool jok = j < count;
    const float* __restrict__ Bp = BdT_T + (jok ? j : 0);

    const float* Ar[8];
    #pragma unroll
    for (int r = 0; r < 8; ++r)
        Ar[r] = vocab_w + (size_t)min(v0 + r, NC_ - 1) * C_;

    float acc[8] = {};
    #pragma unroll 4
    for (int k = 0; k < C_; ++k) {
        float b = Bp[(size_t)k * jcap];
        #pragma unroll
        for (int r = 0; r < 8; ++r) acc[r] += Ar[r][k] * b;
    }

    if (jok) {
        const int hw = idxList[j];
        #pragma unroll
        for (int r = 0; r < 8; ++r) {
            int v = v0 + r;
            if (v < NC_)
                out[CLS_OFF_ + (size_t)v * HW_ + hw] = acc[r] + vocab_b[v];
        }
    }
}

// --------------------------- fallback: direct scatter-gather GEMM (count>jcap)
__global__ __launch_bounds__(256) void k_gemm_fallback(
    const float* __restrict__ cls_feat, const float* __restrict__ vocab_w,
    const float* __restrict__ vocab_b, const int* __restrict__ cnt,
    const int* __restrict__ idxList, float* __restrict__ out, int capB)
{
    const int count = min(*cnt, HW_);
    if (count <= capB) return;  // dense path handled it
    const int v0 = blockIdx.x * 64;

    __shared__ float sAT[16][64];
    __shared__ float sBT[16][64];
    __shared__ int   sIdx[64];

    const int tid = threadIdx.x;
    const int tx = tid & 15;
    const int ty = tid >> 4;
    const int r  = tid >> 2;
    const int kq = tid & 3;

    for (int jb = blockIdx.y; (jb << 6) < count; jb += gridDim.y) {
        const int j0 = jb << 6;
        __syncthreads();
        if (tid < 64) {
            int j = j0 + tid;
            sIdx[tid] = (j < count) ? idxList[j] : -1;
        }
        __syncthreads();
        const int hwj = sIdx[r];

        float acc[4][4] = {};
        for (int k0 = 0; k0 < C_; k0 += 16) {
            float4 a4 = make_float4(0.f, 0.f, 0.f, 0.f);
            if (v0 + r < NC_)
                a4 = *(const float4*)(vocab_w + (size_t)(v0 + r) * C_ + k0 + kq * 4);
            float b0 = 0.f, b1 = 0.f, b2 = 0.f, b3 = 0.f;
            if (hwj >= 0) {
                const float* bp = cls_feat + (size_t)(k0 + kq * 4) * HW_ + hwj;
                b0 = bp[0]; b1 = bp[HW_]; b2 = bp[2 * HW_]; b3 = bp[3 * HW_];
            }
            __syncthreads();
            sAT[kq * 4 + 0][r] = a4.x; sAT[kq * 4 + 1][r] = a4.y;
            sAT[kq * 4 + 2][r] = a4.z; sAT[kq * 4 + 3][r] = a4.w;
            sBT[kq * 4 + 0][r] = b0;   sBT[kq * 4 + 1][r] = b1;
            sBT[kq * 4 + 2][r] = b2;   sBT[kq * 4 + 3][r] = b3;
            __syncthreads();
            #pragma unroll
            for (int kk = 0; kk < 16; ++kk) {
                const float4 av = *(const float4*)&sAT[kk][ty * 4];
                const float4 bv = *(const float4*)&sBT[kk][tx * 4];
                acc[0][0] += av.x * bv.x; acc[0][1] += av.x * bv.y;
                acc[0][2] += av.x * bv.z; acc[0][3] += av.x * bv.w;
                acc[1][0] += av.y * bv.x; acc[1][1] += av.y * bv.y;
                acc[1][2] += av.y * bv.z; acc[1][3] += av.y * bv.w;
                acc[2][0] += av.z * bv.x; acc[2][1] += av.z * bv.y;
                acc[2][2] += av.z * bv.z; acc[2][3] += av.z * bv.w;
                acc[3][0] += av.w * bv.x; acc[3][1] += av.w * bv.y;
                acc[3][2] += av.w * bv.z; acc[3][3] += av.w * bv.w;
            }
        }
        #pragma unroll
        for (int a = 0; a < 4; ++a) {
            int v = v0 + ty * 4 + a;
            if (v >= NC_) continue;
            float bias = vocab_b[v];
            #pragma unroll
            for (int b = 0; b < 4; ++b) {
                int j = j0 + tx * 4 + b;
                if (j < count) {
                    int hw = sIdx[tx * 4 + b];
                    out[CLS_OFF_ + (size_t)v * HW_ + hw] = acc[a][b] + bias;
                }
            }
        }
    }
}

// ----------------------------------------------------------------- launch
extern "C" void kernel_launch(void* const* d_in, const int* in_sizes, int n_in,
                              void* d_out, int out_size, void* d_ws,
                              size_t ws_size, hipStream_t stream) {
    const float* cls_feat = (const float*)d_in[0];
    const float* loc_feat = (const float*)d_in[1];
    const float* conf     = (const float*)d_in[2];
    const float* pf_w     = (const float*)d_in[3];
    const float* pf_b     = (const float*)d_in[4];
    const float* vocab_w  = (const float*)d_in[5];
    const float* vocab_b  = (const float*)d_in[6];
    const float* loc_w    = (const float*)d_in[7];
    const float* loc_b    = (const float*)d_in[8];
    float* out = (float*)d_out;

    int*   cnt     = (int*)d_ws;
    int*   idxList = (int*)((char*)d_ws + 4096);
    size_t fixed   = 4096 + (size_t)HW_ * sizeof(int);
    float* BdT_T   = (float*)((char*)d_ws + fixed);

    int jcap = 0;
    if (ws_size > fixed) {
        size_t cols = (ws_size - fixed) / ((size_t)C_ * sizeof(float));
        jcap = (int)(cols > 1024 ? 1024 : cols);
        jcap &= ~63;
    }

    hipLaunchKernelGGL(k_init, dim3(1), dim3(1), 0, stream, cnt);
    hipLaunchKernelGGL(k_main,
                       dim3(PF_BLOCKS_ + LOC_BLOCKS_ + FILL_BLOCKS_),
                       dim3(256), 0, stream,
                       cls_feat, loc_feat, conf, pf_w, pf_b, vocab_b,
                       loc_w, loc_b, out, cnt, idxList);
    if (jcap > 0) {
        hipLaunchKernelGGL(k_gatherT, dim3(512), dim3(256), 0, stream,
                           cls_feat, cnt, idxList, BdT_T, jcap);
        hipLaunchKernelGGL(k_gemm2, dim3((NC_ + 31) / 32, jcap / 64),
                           dim3(256), 0, stream,
                           vocab_w, vocab_b, cnt, idxList, BdT_T, out, jcap);
    }
    hipLaunchKernelGGL(k_gemm_fallback, dim3((NC_ + 63) / 64, 8), dim3(256),
                       0, stream, cls_feat, vocab_w, vocab_b, cnt, idxList,
                       out, jcap);
}

// Round 8
// 82.683 us; speedup vs baseline: 1.3203x; 1.3203x over previous
//
#include <hip/hip_runtime.h>
#include <math.h>

// LRPCHead: C=512, H=W=160 (HW=25600), NC=1203, LC=64
// Outputs (flat, fp32): loc_out [64*25600] | cls_out [1203*25600] | mask [25600]

constexpr int C_   = 512;
constexpr int HW_  = 25600;
constexpr int NC_  = 1203;

constexpr int LOC_OFF_  = 0;
constexpr int CLS_OFF_  = 64 * HW_;              // 1,638,400
constexpr int MASK_OFF_ = CLS_OFF_ + NC_ * HW_;  // 32,435,200

constexpr int PF_BLOCKS_   = HW_ / 64;   // 400
constexpr int LOC_BLOCKS_  = 400;        // 100 hw-tiles x 4 channel-tiles
constexpr int FILL_BLOCKS_ = 2048;

typedef float vfloat4 __attribute__((ext_vector_type(4)));

// ---------------------------------------------------------------- init
__global__ void k_init(int* cnt) { *cnt = 0; }

// ---------------- fused: pf mask+compact | loc conv | cls bias fill
__global__ __launch_bounds__(256) void k_main(
    const float* __restrict__ cls_feat, const float* __restrict__ loc_feat,
    const float* __restrict__ conf, const float* __restrict__ pf_w,
    const float* __restrict__ pf_b, const float* __restrict__ vocab_b,
    const float* __restrict__ loc_w, const float* __restrict__ loc_b,
    float* __restrict__ out, int* __restrict__ cnt,
    int* __restrict__ idxList)
{
    const int bid = blockIdx.x;
    const int tid = threadIdx.x;

    if (bid < PF_BLOCKS_) {
        // ---------------- pf score + mask + compact
        __shared__ double sPart[256];
        const int hwi   = tid & 63;
        const int slice = tid >> 6;
        const int hw    = bid * 64 + hwi;
        const float* p  = cls_feat + (size_t)slice * 128 * HW_ + hw;
        const float* w  = pf_w + slice * 128;
        double acc = 0.0;
        #pragma unroll 4
        for (int k = 0; k < 128; ++k)
            acc += (double)w[k] * (double)p[(size_t)k * HW_];
        sPart[tid] = acc;
        __syncthreads();
        if (slice == 0) {
            double s = sPart[hwi] + sPart[64 + hwi] + sPart[128 + hwi] +
                       sPart[192 + hwi] + (double)pf_b[0];
            double sig = 1.0 / (1.0 + exp(-s));
            bool m = sig > (double)conf[0];
            out[MASK_OFF_ + hw] = m ? 1.0f : 0.0f;
            if (m) {
                int pos = atomicAdd(cnt, 1);
                if (pos < HW_) idxList[pos] = hw;
            }
        }
    } else if (bid < PF_BLOCKS_ + LOC_BLOCKS_) {
        // ---------------- loc 1x1 conv (64x64)
        const int j   = bid - PF_BLOCKS_;
        const int hwb = j % 100;
        const int o0  = (j / 100) * 16;
        __shared__ float sw[16][64];
        for (int i = tid; i < 16 * 64; i += 256)
            sw[i >> 6][i & 63] = loc_w[(o0 + (i >> 6)) * 64 + (i & 63)];
        __syncthreads();
        const int hw = hwb * 256 + tid;
        float acc[16];
        #pragma unroll
        for (int r = 0; r < 16; ++r) acc[r] = loc_b[o0 + r];
        for (int i = 0; i < 64; ++i) {
            float f = loc_feat[(size_t)i * HW_ + hw];
            #pragma unroll
            for (int r = 0; r < 16; ++r) acc[r] += sw[r][i] * f;
        }
        #pragma unroll
        for (int r = 0; r < 16; ++r)
            out[LOC_OFF_ + (size_t)(o0 + r) * HW_ + hw] = acc[r];
    } else {
        // ---------------- fill cls_out with vocab_b (nontemporal)
        const int fb = bid - PF_BLOCKS_ - LOC_BLOCKS_;
        const int total4 = NC_ * HW_ / 4;  // 7,699,200 float4s
        vfloat4* o = (vfloat4*)(out + CLS_OFF_);
        for (int i = fb * 256 + tid; i < total4; i += FILL_BLOCKS_ * 256) {
            int v = i / (HW_ / 4);
            float b = vocab_b[v];
            vfloat4 val = {b, b, b, b};
            __builtin_nontemporal_store(val, &o[i]);
        }
    }
}

// ------------- gather live columns TRANSPOSED: BdT_T[k][j], stride jcap
__global__ __launch_bounds__(256) void k_gatherT(
    const float* __restrict__ cls_feat, const int* __restrict__ cnt,
    const int* __restrict__ idxList, float* __restrict__ BdT_T, int jcap)
{
    const int count = min(*cnt, HW_);
    if (count > jcap) return;  // fallback path will handle
    const int t = threadIdx.x;
    for (int j = blockIdx.x; j < count; j += gridDim.x) {
        const int hw = idxList[j];
        BdT_T[(size_t)t * jcap + j]         = cls_feat[(size_t)t * HW_ + hw];
        BdT_T[(size_t)(256 + t) * jcap + j] = cls_feat[(size_t)(256 + t) * HW_ + hw];
    }
}

// ------------- dense GEMM: 1 wave/block, 4 v-rows per wave (uniform scalar A),
// lane->j (coalesced B), 2 k-phase accumulators x unroll 8 = 16 loads in flight.
// grid (ceil(NC/4), jcap/64); dead j-blocks exit immediately.
__global__ __launch_bounds__(64) void k_gemm2(
    const float* __restrict__ vocab_w, const float* __restrict__ vocab_b,
    const int* __restrict__ cnt, const int* __restrict__ idxList,
    const float* __restrict__ BdT_T, float* __restrict__ out, int jcap)
{
    const int count = min(*cnt, HW_);
    if (count == 0 || count > jcap) return;
    const int j0 = blockIdx.y * 64;
    if (j0 >= count) return;

    const int v0   = blockIdx.x * 4;
    const int lane = threadIdx.x;
    const int j    = j0 + lane;
    const bool jok = j < count;
    const float* __restrict__ Bp = BdT_T + (jok ? j : 0);

    const float* Ar[4];
    #pragma unroll
    for (int r = 0; r < 4; ++r)
        Ar[r] = vocab_w + (size_t)min(v0 + r, NC_ - 1) * C_;

    float acc0[4] = {}, acc1[4] = {};
    #pragma unroll 8
    for (int k = 0; k < C_; k += 2) {
        const float b0 = Bp[(size_t)k * jcap];
        const float b1 = Bp[(size_t)(k + 1) * jcap];
        #pragma unroll
        for (int r = 0; r < 4; ++r) {
            acc0[r] += Ar[r][k] * b0;
            acc1[r] += Ar[r][k + 1] * b1;
        }
    }

    if (jok) {
        const int hw = idxList[j];
        #pragma unroll
        for (int r = 0; r < 4; ++r) {
            const int v = v0 + r;
            if (v < NC_)
                out[CLS_OFF_ + (size_t)v * HW_ + hw] =
                    acc0[r] + acc1[r] + vocab_b[v];
        }
    }
}

// --------------------------- fallback: direct scatter-gather GEMM (count>jcap)
__global__ __launch_bounds__(256) void k_gemm_fallback(
    const float* __restrict__ cls_feat, const float* __restrict__ vocab_w,
    const float* __restrict__ vocab_b, const int* __restrict__ cnt,
    const int* __restrict__ idxList, float* __restrict__ out, int capB)
{
    const int count = min(*cnt, HW_);
    if (count <= capB) return;  // dense path handled it
    const int v0 = blockIdx.x * 64;

    __shared__ float sAT[16][64];
    __shared__ float sBT[16][64];
    __shared__ int   sIdx[64];

    const int tid = threadIdx.x;
    const int tx = tid & 15;
    const int ty = tid >> 4;
    const int r  = tid >> 2;
    const int kq = tid & 3;

    for (int jb = blockIdx.y; (jb << 6) < count; jb += gridDim.y) {
        const int j0 = jb << 6;
        __syncthreads();
        if (tid < 64) {
            int j = j0 + tid;
            sIdx[tid] = (j < count) ? idxList[j] : -1;
        }
        __syncthreads();
        const int hwj = sIdx[r];

        float acc[4][4] = {};
        for (int k0 = 0; k0 < C_; k0 += 16) {
            float4 a4 = make_float4(0.f, 0.f, 0.f, 0.f);
            if (v0 + r < NC_)
                a4 = *(const float4*)(vocab_w + (size_t)(v0 + r) * C_ + k0 + kq * 4);
            float b0 = 0.f, b1 = 0.f, b2 = 0.f, b3 = 0.f;
            if (hwj >= 0) {
                const float* bp = cls_feat + (size_t)(k0 + kq * 4) * HW_ + hwj;
                b0 = bp[0]; b1 = bp[HW_]; b2 = bp[2 * HW_]; b3 = bp[3 * HW_];
            }
            __syncthreads();
            sAT[kq * 4 + 0][r] = a4.x; sAT[kq * 4 + 1][r] = a4.y;
            sAT[kq * 4 + 2][r] = a4.z; sAT[kq * 4 + 3][r] = a4.w;
            sBT[kq * 4 + 0][r] = b0;   sBT[kq * 4 + 1][r] = b1;
            sBT[kq * 4 + 2][r] = b2;   sBT[kq * 4 + 3][r] = b3;
            __syncthreads();
            #pragma unroll
            for (int kk = 0; kk < 16; ++kk) {
                const float4 av = *(const float4*)&sAT[kk][ty * 4];
                const float4 bv = *(const float4*)&sBT[kk][tx * 4];
                acc[0][0] += av.x * bv.x; acc[0][1] += av.x * bv.y;
                acc[0][2] += av.x * bv.z; acc[0][3] += av.x * bv.w;
                acc[1][0] += av.y * bv.x; acc[1][1] += av.y * bv.y;
                acc[1][2] += av.y * bv.z; acc[1][3] += av.y * bv.w;
                acc[2][0] += av.z * bv.x; acc[2][1] += av.z * bv.y;
                acc[2][2] += av.z * bv.z; acc[2][3] += av.z * bv.w;
                acc[3][0] += av.w * bv.x; acc[3][1] += av.w * bv.y;
                acc[3][2] += av.w * bv.z; acc[3][3] += av.w * bv.w;
            }
        }
        #pragma unroll
        for (int a = 0; a < 4; ++a) {
            int v = v0 + ty * 4 + a;
            if (v >= NC_) continue;
            float bias = vocab_b[v];
            #pragma unroll
            for (int b = 0; b < 4; ++b) {
                int j = j0 + tx * 4 + b;
                if (j < count) {
                    int hw = sIdx[tx * 4 + b];
                    out[CLS_OFF_ + (size_t)v * HW_ + hw] = acc[a][b] + bias;
                }
            }
        }
    }
}

// ----------------------------------------------------------------- launch
extern "C" void kernel_launch(void* const* d_in, const int* in_sizes, int n_in,
                              void* d_out, int out_size, void* d_ws,
                              size_t ws_size, hipStream_t stream) {
    const float* cls_feat = (const float*)d_in[0];
    const float* loc_feat = (const float*)d_in[1];
    const float* conf     = (const float*)d_in[2];
    const float* pf_w     = (const float*)d_in[3];
    const float* pf_b     = (const float*)d_in[4];
    const float* vocab_w  = (const float*)d_in[5];
    const float* vocab_b  = (const float*)d_in[6];
    const float* loc_w    = (const float*)d_in[7];
    const float* loc_b    = (const float*)d_in[8];
    float* out = (float*)d_out;

    int*   cnt     = (int*)d_ws;
    int*   idxList = (int*)((char*)d_ws + 4096);
    size_t fixed   = 4096 + (size_t)HW_ * sizeof(int);
    float* BdT_T   = (float*)((char*)d_ws + fixed);

    int jcap = 0;
    if (ws_size > fixed) {
        size_t cols = (ws_size - fixed) / ((size_t)C_ * sizeof(float));
        jcap = (int)(cols > 1024 ? 1024 : cols);
        jcap &= ~63;
    }

    hipLaunchKernelGGL(k_init, dim3(1), dim3(1), 0, stream, cnt);
    hipLaunchKernelGGL(k_main,
                       dim3(PF_BLOCKS_ + LOC_BLOCKS_ + FILL_BLOCKS_),
                       dim3(256), 0, stream,
                       cls_feat, loc_feat, conf, pf_w, pf_b, vocab_b,
                       loc_w, loc_b, out, cnt, idxList);
    if (jcap > 0) {
        hipLaunchKernelGGL(k_gatherT, dim3(512), dim3(256), 0, stream,
                           cls_feat, cnt, idxList, BdT_T, jcap);
        hipLaunchKernelGGL(k_gemm2, dim3((NC_ + 3) / 4, jcap / 64),
                           dim3(64), 0, stream,
                           vocab_w, vocab_b, cnt, idxList, BdT_T, out, jcap);
    }
    hipLaunchKernelGGL(k_gemm_fallback, dim3((NC_ + 63) / 64, 8), dim3(256),
                       0, stream, cls_feat, vocab_w, vocab_b, cnt, idxList,
                       out, jcap);
}

// Round 9
// 74.695 us; speedup vs baseline: 1.4616x; 1.1070x over previous
//
#include <hip/hip_runtime.h>
#include <math.h>

// LRPCHead: C=512, H=W=160 (HW=25600), NC=1203, LC=64
// Outputs (flat, fp32): loc_out [64*25600] | cls_out [1203*25600] | mask [25600]

constexpr int C_   = 512;
constexpr int HW_  = 25600;
constexpr int NC_  = 1203;

constexpr int LOC_OFF_  = 0;
constexpr int CLS_OFF_  = 64 * HW_;              // 1,638,400
constexpr int MASK_OFF_ = CLS_OFF_ + NC_ * HW_;  // 32,435,200

constexpr int PF_BLOCKS_   = HW_ / 64;   // 400
constexpr int LOC_BLOCKS_  = 400;        // 100 hw-tiles x 4 channel-tiles
constexpr int FILL_BLOCKS_ = 2048;

typedef float vfloat4 __attribute__((ext_vector_type(4)));

// ---------------------------------------------------------------- init
__global__ void k_init(int* cnt) { *cnt = 0; }

// ---------------- fused: pf mask+compact | loc conv | cls bias fill
// (verbatim round-8 body)
__global__ __launch_bounds__(256) void k_main(
    const float* __restrict__ cls_feat, const float* __restrict__ loc_feat,
    const float* __restrict__ conf, const float* __restrict__ pf_w,
    const float* __restrict__ pf_b, const float* __restrict__ vocab_b,
    const float* __restrict__ loc_w, const float* __restrict__ loc_b,
    float* __restrict__ out, int* __restrict__ cnt,
    int* __restrict__ idxList)
{
    const int bid = blockIdx.x;
    const int tid = threadIdx.x;

    if (bid < PF_BLOCKS_) {
        __shared__ double sPart[256];
        const int hwi   = tid & 63;
        const int slice = tid >> 6;
        const int hw    = bid * 64 + hwi;
        const float* p  = cls_feat + (size_t)slice * 128 * HW_ + hw;
        const float* w  = pf_w + slice * 128;
        double acc = 0.0;
        #pragma unroll 4
        for (int k = 0; k < 128; ++k)
            acc += (double)w[k] * (double)p[(size_t)k * HW_];
        sPart[tid] = acc;
        __syncthreads();
        if (slice == 0) {
            double s = sPart[hwi] + sPart[64 + hwi] + sPart[128 + hwi] +
                       sPart[192 + hwi] + (double)pf_b[0];
            double sig = 1.0 / (1.0 + exp(-s));
            bool m = sig > (double)conf[0];
            out[MASK_OFF_ + hw] = m ? 1.0f : 0.0f;
            if (m) {
                int pos = atomicAdd(cnt, 1);
                if (pos < HW_) idxList[pos] = hw;
            }
        }
    } else if (bid < PF_BLOCKS_ + LOC_BLOCKS_) {
        const int j   = bid - PF_BLOCKS_;
        const int hwb = j % 100;
        const int o0  = (j / 100) * 16;
        __shared__ float sw[16][64];
        for (int i = tid; i < 16 * 64; i += 256)
            sw[i >> 6][i & 63] = loc_w[(o0 + (i >> 6)) * 64 + (i & 63)];
        __syncthreads();
        const int hw = hwb * 256 + tid;
        float acc[16];
        #pragma unroll
        for (int r = 0; r < 16; ++r) acc[r] = loc_b[o0 + r];
        for (int i = 0; i < 64; ++i) {
            float f = loc_feat[(size_t)i * HW_ + hw];
            #pragma unroll
            for (int r = 0; r < 16; ++r) acc[r] += sw[r][i] * f;
        }
        #pragma unroll
        for (int r = 0; r < 16; ++r)
            out[LOC_OFF_ + (size_t)(o0 + r) * HW_ + hw] = acc[r];
    } else {
        const int fb = bid - PF_BLOCKS_ - LOC_BLOCKS_;
        const int total4 = NC_ * HW_ / 4;  // 7,699,200 float4s
        vfloat4* o = (vfloat4*)(out + CLS_OFF_);
        for (int i = fb * 256 + tid; i < total4; i += FILL_BLOCKS_ * 256) {
            int v = i / (HW_ / 4);
            float b = vocab_b[v];
            vfloat4 val = {b, b, b, b};
            __builtin_nontemporal_store(val, &o[i]);
        }
    }
}

// ------------- gather live columns TRANSPOSED: BdT_T[k][j], row stride bstr
__global__ __launch_bounds__(256) void k_gatherT(
    const float* __restrict__ cls_feat, const int* __restrict__ cnt,
    const int* __restrict__ idxList, float* __restrict__ BdT_T, int jcap,
    int bstr)
{
    const int count = min(*cnt, HW_);
    if (count > jcap) return;  // fallback path will handle
    const int t = threadIdx.x;
    for (int j = blockIdx.x; j < count; j += gridDim.x) {
        const int hw = idxList[j];
        BdT_T[(size_t)t * bstr + j]         = cls_feat[(size_t)t * HW_ + hw];
        BdT_T[(size_t)(256 + t) * bstr + j] = cls_feat[(size_t)(256 + t) * HW_ + hw];
    }
}

// ------------- dense GEMM, LDS-staged: block = 16 v-rows x 64 j-cols,
// K in 4 chunks of 128 via Bs[128][64] (32 KB). A is wave-uniform (s_load).
// grid (ceil(NC/16), jcap/64); dead j-blocks exit immediately.
__global__ __launch_bounds__(256) void k_gemm3(
    const float* __restrict__ vocab_w, const float* __restrict__ vocab_b,
    const int* __restrict__ cnt, const int* __restrict__ idxList,
    const float* __restrict__ BdT_T, float* __restrict__ out, int jcap,
    int bstr)
{
    const int count = min(*cnt, HW_);
    if (count == 0 || count > jcap) return;
    const int j0 = blockIdx.y * 64;
    if (j0 >= count) return;

    __shared__ float Bs[128][64];

    const int tid = threadIdx.x;
    const int w   = tid >> 6;   // wave 0..3
    const int l   = tid & 63;   // lane = j offset
    const int v0  = blockIdx.x * 16;

    const float* A[4];
    #pragma unroll
    for (int r = 0; r < 4; ++r)
        A[r] = vocab_w + (size_t)min(v0 + w * 4 + r, NC_ - 1) * C_;

    const int rr = tid >> 4;   // staging row within 16-row pass
    const int qq = tid & 15;   // float4 quad within row

    float acc[4] = {};

    for (int c = 0; c < 4; ++c) {
        __syncthreads();  // previous chunk's reads done
        #pragma unroll
        for (int p = 0; p < 8; ++p) {
            const int row = p * 16 + rr;
            const float* src =
                BdT_T + (size_t)(c * 128 + row) * bstr + j0 + qq * 4;
            *(vfloat4*)&Bs[row][qq * 4] = *(const vfloat4*)src;
        }
        __syncthreads();
        const int kb = c * 128;
        #pragma unroll 8
        for (int kk = 0; kk < 128; ++kk) {
            const float b = Bs[kk][l];
            #pragma unroll
            for (int r = 0; r < 4; ++r)
                acc[r] += A[r][kb + kk] * b;
        }
    }

    const int j = j0 + l;
    if (j < count) {
        const int hw = idxList[j];
        #pragma unroll
        for (int r = 0; r < 4; ++r) {
            const int v = v0 + w * 4 + r;
            if (v < NC_)
                out[CLS_OFF_ + (size_t)v * HW_ + hw] = acc[r] + vocab_b[v];
        }
    }
}

// --------------------------- fallback: direct scatter-gather GEMM (count>jcap)
__global__ __launch_bounds__(256) void k_gemm_fallback(
    const float* __restrict__ cls_feat, const float* __restrict__ vocab_w,
    const float* __restrict__ vocab_b, const int* __restrict__ cnt,
    const int* __restrict__ idxList, float* __restrict__ out, int capB)
{
    const int count = min(*cnt, HW_);
    if (count <= capB) return;  // dense path handled it
    const int v0 = blockIdx.x * 64;

    __shared__ float sAT[16][64];
    __shared__ float sBT[16][64];
    __shared__ int   sIdx[64];

    const int tid = threadIdx.x;
    const int tx = tid & 15;
    const int ty = tid >> 4;
    const int r  = tid >> 2;
    const int kq = tid & 3;

    for (int jb = blockIdx.y; (jb << 6) < count; jb += gridDim.y) {
        const int j0 = jb << 6;
        __syncthreads();
        if (tid < 64) {
            int j = j0 + tid;
            sIdx[tid] = (j < count) ? idxList[j] : -1;
        }
        __syncthreads();
        const int hwj = sIdx[r];

        float acc[4][4] = {};
        for (int k0 = 0; k0 < C_; k0 += 16) {
            float4 a4 = make_float4(0.f, 0.f, 0.f, 0.f);
            if (v0 + r < NC_)
                a4 = *(const float4*)(vocab_w + (size_t)(v0 + r) * C_ + k0 + kq * 4);
            float b0 = 0.f, b1 = 0.f, b2 = 0.f, b3 = 0.f;
            if (hwj >= 0) {
                const float* bp = cls_feat + (size_t)(k0 + kq * 4) * HW_ + hwj;
                b0 = bp[0]; b1 = bp[HW_]; b2 = bp[2 * HW_]; b3 = bp[3 * HW_];
            }
            __syncthreads();
            sAT[kq * 4 + 0][r] = a4.x; sAT[kq * 4 + 1][r] = a4.y;
            sAT[kq * 4 + 2][r] = a4.z; sAT[kq * 4 + 3][r] = a4.w;
            sBT[kq * 4 + 0][r] = b0;   sBT[kq * 4 + 1][r] = b1;
            sBT[kq * 4 + 2][r] = b2;   sBT[kq * 4 + 3][r] = b3;
            __syncthreads();
            #pragma unroll
            for (int kk = 0; kk < 16; ++kk) {
                const float4 av = *(const float4*)&sAT[kk][ty * 4];
                const float4 bv = *(const float4*)&sBT[kk][tx * 4];
                acc[0][0] += av.x * bv.x; acc[0][1] += av.x * bv.y;
                acc[0][2] += av.x * bv.z; acc[0][3] += av.x * bv.w;
                acc[1][0] += av.y * bv.x; acc[1][1] += av.y * bv.y;
                acc[1][2] += av.y * bv.z; acc[1][3] += av.y * bv.w;
                acc[2][0] += av.z * bv.x; acc[2][1] += av.z * bv.y;
                acc[2][2] += av.z * bv.z; acc[2][3] += av.z * bv.w;
                acc[3][0] += av.w * bv.x; acc[3][1] += av.w * bv.y;
                acc[3][2] += av.w * bv.z; acc[3][3] += av.w * bv.w;
            }
        }
        #pragma unroll
        for (int a = 0; a < 4; ++a) {
            int v = v0 + ty * 4 + a;
            if (v >= NC_) continue;
            float bias = vocab_b[v];
            #pragma unroll
            for (int b = 0; b < 4; ++b) {
                int j = j0 + tx * 4 + b;
                if (j < count) {
                    int hw = sIdx[tx * 4 + b];
                    out[CLS_OFF_ + (size_t)v * HW_ + hw] = acc[a][b] + bias;
                }
            }
        }
    }
}

// ----------------------------------------------------------------- launch
extern "C" void kernel_launch(void* const* d_in, const int* in_sizes, int n_in,
                              void* d_out, int out_size, void* d_ws,
                              size_t ws_size, hipStream_t stream) {
    const float* cls_feat = (const float*)d_in[0];
    const float* loc_feat = (const float*)d_in[1];
    const float* conf     = (const float*)d_in[2];
    const float* pf_w     = (const float*)d_in[3];
    const float* pf_b     = (const float*)d_in[4];
    const float* vocab_w  = (const float*)d_in[5];
    const float* vocab_b  = (const float*)d_in[6];
    const float* loc_w    = (const float*)d_in[7];
    const float* loc_b    = (const float*)d_in[8];
    float* out = (float*)d_out;

    int*   cnt     = (int*)d_ws;
    int*   idxList = (int*)((char*)d_ws + 4096);
    size_t fixed   = 4096 + (size_t)HW_ * sizeof(int);
    float* BdT_T   = (float*)((char*)d_ws + fixed);

    int jcap = 0, bstr = 0;
    if (ws_size > fixed) {
        size_t cols = (ws_size - fixed) / ((size_t)C_ * sizeof(float));
        if (cols >= 1040)       { jcap = 1024; bstr = 1040; }  // padded stride
        else                    { jcap = (int)cols & ~63; bstr = jcap; }
    }

    hipLaunchKernelGGL(k_init, dim3(1), dim3(1), 0, stream, cnt);
    hipLaunchKernelGGL(k_main,
                       dim3(PF_BLOCKS_ + LOC_BLOCKS_ + FILL_BLOCKS_),
                       dim3(256), 0, stream,
                       cls_feat, loc_feat, conf, pf_w, pf_b, vocab_b,
                       loc_w, loc_b, out, cnt, idxList);
    if (jcap > 0) {
        hipLaunchKernelGGL(k_gatherT, dim3(512), dim3(256), 0, stream,
                           cls_feat, cnt, idxList, BdT_T, jcap, bstr);
        hipLaunchKernelGGL(k_gemm3, dim3((NC_ + 15) / 16, jcap / 64),
                           dim3(256), 0, stream,
                           vocab_w, vocab_b, cnt, idxList, BdT_T, out,
                           jcap, bstr);
    }
    hipLaunchKernelGGL(k_gemm_fallback, dim3((NC_ + 63) / 64, 8), dim3(256),
                       0, stream, cls_feat, vocab_w, vocab_b, cnt, idxList,
                       out, jcap);
}

// Round 10
// 72.014 us; speedup vs baseline: 1.5160x; 1.0372x over previous
//
#include <hip/hip_runtime.h>
#include <math.h>

// LRPCHead: C=512, H=W=160 (HW=25600), NC=1203, LC=64
// Outputs (flat, fp32): loc_out [64*25600] | cls_out [1203*25600] | mask [25600]

constexpr int C_   = 512;
constexpr int HW_  = 25600;
constexpr int NC_  = 1203;
constexpr int VPAD_ = 1216;   // padded v-extent for AT (19*64)

constexpr int LOC_OFF_  = 0;
constexpr int CLS_OFF_  = 64 * HW_;              // 1,638,400
constexpr int MASK_OFF_ = CLS_OFF_ + NC_ * HW_;  // 32,435,200

constexpr int PF_BLOCKS_    = HW_ / 64;  // 400
constexpr int LOC_BLOCKS_   = 400;       // 100 hw-tiles x 4 channel-tiles
constexpr int FILL_BLOCKS_  = 2048;
constexpr int TRANS_BLOCKS_ = 19 * 8;    // 152: v-tiles x k-tiles of 64

typedef float vfloat4 __attribute__((ext_vector_type(4)));

// ---------------------------------------------------------------- init
__global__ void k_init(int* cnt) { *cnt = 0; }

// ---- fused: pf mask+compact | loc conv | cls bias fill | vocab transpose
__global__ __launch_bounds__(256) void k_main(
    const float* __restrict__ cls_feat, const float* __restrict__ loc_feat,
    const float* __restrict__ conf, const float* __restrict__ pf_w,
    const float* __restrict__ pf_b, const float* __restrict__ vocab_w,
    const float* __restrict__ vocab_b, const float* __restrict__ loc_w,
    const float* __restrict__ loc_b, float* __restrict__ out,
    int* __restrict__ cnt, int* __restrict__ idxList,
    float* __restrict__ AT4, int jcap)
{
    const int bid = blockIdx.x;
    const int tid = threadIdx.x;

    if (bid < PF_BLOCKS_) {
        // ---------------- pf score + mask + compact (proven body)
        __shared__ double sPart[256];
        const int hwi   = tid & 63;
        const int slice = tid >> 6;
        const int hw    = bid * 64 + hwi;
        const float* p  = cls_feat + (size_t)slice * 128 * HW_ + hw;
        const float* w  = pf_w + slice * 128;
        double acc = 0.0;
        #pragma unroll 4
        for (int k = 0; k < 128; ++k)
            acc += (double)w[k] * (double)p[(size_t)k * HW_];
        sPart[tid] = acc;
        __syncthreads();
        if (slice == 0) {
            double s = sPart[hwi] + sPart[64 + hwi] + sPart[128 + hwi] +
                       sPart[192 + hwi] + (double)pf_b[0];
            double sig = 1.0 / (1.0 + exp(-s));
            bool m = sig > (double)conf[0];
            out[MASK_OFF_ + hw] = m ? 1.0f : 0.0f;
            if (m) {
                int pos = atomicAdd(cnt, 1);
                if (pos < HW_) idxList[pos] = hw;
            }
        }
    } else if (bid < PF_BLOCKS_ + LOC_BLOCKS_) {
        // ---------------- loc 1x1 conv (proven body)
        const int j   = bid - PF_BLOCKS_;
        const int hwb = j % 100;
        const int o0  = (j / 100) * 16;
        __shared__ float sw[16][64];
        for (int i = tid; i < 16 * 64; i += 256)
            sw[i >> 6][i & 63] = loc_w[(o0 + (i >> 6)) * 64 + (i & 63)];
        __syncthreads();
        const int hw = hwb * 256 + tid;
        float acc[16];
        #pragma unroll
        for (int r = 0; r < 16; ++r) acc[r] = loc_b[o0 + r];
        for (int i = 0; i < 64; ++i) {
            float f = loc_feat[(size_t)i * HW_ + hw];
            #pragma unroll
            for (int r = 0; r < 16; ++r) acc[r] += sw[r][i] * f;
        }
        #pragma unroll
        for (int r = 0; r < 16; ++r)
            out[LOC_OFF_ + (size_t)(o0 + r) * HW_ + hw] = acc[r];
    } else if (bid < PF_BLOCKS_ + LOC_BLOCKS_ + FILL_BLOCKS_) {
        // ---------------- fill cls_out with vocab_b (proven body)
        const int fb = bid - PF_BLOCKS_ - LOC_BLOCKS_;
        const int total4 = NC_ * HW_ / 4;  // 7,699,200 float4s
        vfloat4* o = (vfloat4*)(out + CLS_OFF_);
        for (int i = fb * 256 + tid; i < total4; i += FILL_BLOCKS_ * 256) {
            int v = i / (HW_ / 4);
            float b = vocab_b[v];
            vfloat4 val = {b, b, b, b};
            __builtin_nontemporal_store(val, &o[i]);
        }
    } else {
        // ---------------- transpose vocab_w -> AT4[(k/4)][v][4]
        // Independent of all other blocks (reads inputs only).
        if (jcap <= 0) return;
        const int tb = bid - PF_BLOCKS_ - LOC_BLOCKS_ - FILL_BLOCKS_;
        const int v0 = (tb % 19) * 64;
        const int k0 = (tb / 19) * 64;
        __shared__ float t[64][65];
        const int c  = tid & 63;
        const int r4 = tid >> 6;
        #pragma unroll
        for (int i = 0; i < 16; ++i) {
            const int r = r4 * 16 + i;
            const int v = v0 + r;
            t[r][c] = (v < NC_) ? vocab_w[(size_t)v * C_ + k0 + c] : 0.f;
        }
        __syncthreads();
        #pragma unroll
        for (int i = 0; i < 16; ++i) {
            const int k = r4 * 16 + i;           // local k
            const int kg = k0 + k;               // global k
            // AT4 element (kg, v0+c) at ((kg>>2)*VPAD + v)*4 + (kg&3)
            AT4[((size_t)(kg >> 2) * VPAD_ + v0 + c) * 4 + (kg & 3)] = t[c][k];
        }
    }
}

// ------------- gather live columns j-major: BdT[j][k] (contiguous 2KB/col)
__global__ __launch_bounds__(256) void k_gatherJ(
    const float* __restrict__ cls_feat, const int* __restrict__ cnt,
    const int* __restrict__ idxList, float* __restrict__ BdT, int jcap)
{
    const int count = min(*cnt, HW_);
    if (count > jcap) return;  // fallback path will handle
    const int t = threadIdx.x;
    for (int j = blockIdx.x; j < count; j += gridDim.x) {
        const int hw = idxList[j];
        BdT[(size_t)j * C_ + t]       = cls_feat[(size_t)t * HW_ + hw];
        BdT[(size_t)j * C_ + 256 + t] = cls_feat[(size_t)(256 + t) * HW_ + hw];
    }
}

// ------------- dense GEMM: lane->v (coalesced dwordx4 A), wave-uniform j
// (s_load B column). No LDS, no barriers. grid (19, 64); 4 j per block/iter.
__global__ __launch_bounds__(256) void k_gemm4(
    const float* __restrict__ AT4, const float* __restrict__ vocab_b,
    const int* __restrict__ cnt, const int* __restrict__ idxList,
    const float* __restrict__ BdT, float* __restrict__ out, int jcap)
{
    const int count = min(*cnt, HW_);
    if (count == 0 || count > jcap) return;

    const int tid  = threadIdx.x;
    const int lane = tid & 63;
    const int w    = tid >> 6;
    const int v0   = blockIdx.x * 64;
    const int v    = v0 + lane;
    const float* __restrict__ Acol = AT4 + (size_t)(v0 + lane) * 4;

    for (int j4 = blockIdx.y * 4; j4 < count; j4 += 4 * (int)gridDim.y) {
        const int j    = __builtin_amdgcn_readfirstlane(j4 + w);
        const bool jok = j < count;
        const float* __restrict__ Bj = BdT + (size_t)(jok ? j : 0) * C_;

        float ac0 = 0.f, ac1 = 0.f, ac2 = 0.f, ac3 = 0.f;
        #pragma unroll 8
        for (int kq = 0; kq < C_ / 4; ++kq) {
            const vfloat4 a =
                *(const vfloat4*)(Acol + (size_t)kq * VPAD_ * 4);
            ac0 += a.x * Bj[kq * 4 + 0];
            ac1 += a.y * Bj[kq * 4 + 1];
            ac2 += a.z * Bj[kq * 4 + 2];
            ac3 += a.w * Bj[kq * 4 + 3];
        }

        if (jok && v < NC_) {
            const int hw = idxList[j];
            out[CLS_OFF_ + (size_t)v * HW_ + hw] =
                (ac0 + ac1) + (ac2 + ac3) + vocab_b[v];
        }
    }
}

// --------------------------- fallback: direct scatter-gather GEMM (count>jcap)
__global__ __launch_bounds__(256) void k_gemm_fallback(
    const float* __restrict__ cls_feat, const float* __restrict__ vocab_w,
    const float* __restrict__ vocab_b, const int* __restrict__ cnt,
    const int* __restrict__ idxList, float* __restrict__ out, int capB)
{
    const int count = min(*cnt, HW_);
    if (count <= capB) return;  // dense path handled it
    const int v0 = blockIdx.x * 64;

    __shared__ float sAT[16][64];
    __shared__ float sBT[16][64];
    __shared__ int   sIdx[64];

    const int tid = threadIdx.x;
    const int tx = tid & 15;
    const int ty = tid >> 4;
    const int r  = tid >> 2;
    const int kq = tid & 3;

    for (int jb = blockIdx.y; (jb << 6) < count; jb += gridDim.y) {
        const int j0 = jb << 6;
        __syncthreads();
        if (tid < 64) {
            int j = j0 + tid;
            sIdx[tid] = (j < count) ? idxList[j] : -1;
        }
        __syncthreads();
        const int hwj = sIdx[r];

        float acc[4][4] = {};
        for (int k0 = 0; k0 < C_; k0 += 16) {
            float4 a4 = make_float4(0.f, 0.f, 0.f, 0.f);
            if (v0 + r < NC_)
                a4 = *(const float4*)(vocab_w + (size_t)(v0 + r) * C_ + k0 + kq * 4);
            float b0 = 0.f, b1 = 0.f, b2 = 0.f, b3 = 0.f;
            if (hwj >= 0) {
                const float* bp = cls_feat + (size_t)(k0 + kq * 4) * HW_ + hwj;
                b0 = bp[0]; b1 = bp[HW_]; b2 = bp[2 * HW_]; b3 = bp[3 * HW_];
            }
            __syncthreads();
            sAT[kq * 4 + 0][r] = a4.x; sAT[kq * 4 + 1][r] = a4.y;
            sAT[kq * 4 + 2][r] = a4.z; sAT[kq * 4 + 3][r] = a4.w;
            sBT[kq * 4 + 0][r] = b0;   sBT[kq * 4 + 1][r] = b1;
            sBT[kq * 4 + 2][r] = b2;   sBT[kq * 4 + 3][r] = b3;
            __syncthreads();
            #pragma unroll
            for (int kk = 0; kk < 16; ++kk) {
                const float4 av = *(const float4*)&sAT[kk][ty * 4];
                const float4 bv = *(const float4*)&sBT[kk][tx * 4];
                acc[0][0] += av.x * bv.x; acc[0][1] += av.x * bv.y;
                acc[0][2] += av.x * bv.z; acc[0][3] += av.x * bv.w;
                acc[1][0] += av.y * bv.x; acc[1][1] += av.y * bv.y;
                acc[1][2] += av.y * bv.z; acc[1][3] += av.y * bv.w;
                acc[2][0] += av.z * bv.x; acc[2][1] += av.z * bv.y;
                acc[2][2] += av.z * bv.z; acc[2][3] += av.z * bv.w;
                acc[3][0] += av.w * bv.x; acc[3][1] += av.w * bv.y;
                acc[3][2] += av.w * bv.z; acc[3][3] += av.w * bv.w;
            }
        }
        #pragma unroll
        for (int a = 0; a < 4; ++a) {
            int v = v0 + ty * 4 + a;
            if (v >= NC_) continue;
            float bias = vocab_b[v];
            #pragma unroll
            for (int b = 0; b < 4; ++b) {
                int j = j0 + tx * 4 + b;
                if (j < count) {
                    int hw = sIdx[tx * 4 + b];
                    out[CLS_OFF_ + (size_t)v * HW_ + hw] = acc[a][b] + bias;
                }
            }
        }
    }
}

// ----------------------------------------------------------------- launch
extern "C" void kernel_launch(void* const* d_in, const int* in_sizes, int n_in,
                              void* d_out, int out_size, void* d_ws,
                              size_t ws_size, hipStream_t stream) {
    const float* cls_feat = (const float*)d_in[0];
    const float* loc_feat = (const float*)d_in[1];
    const float* conf     = (const float*)d_in[2];
    const float* pf_w     = (const float*)d_in[3];
    const float* pf_b     = (const float*)d_in[4];
    const float* vocab_w  = (const float*)d_in[5];
    const float* vocab_b  = (const float*)d_in[6];
    const float* loc_w    = (const float*)d_in[7];
    const float* loc_b    = (const float*)d_in[8];
    float* out = (float*)d_out;

    int*   cnt     = (int*)d_ws;
    int*   idxList = (int*)((char*)d_ws + 4096);
    size_t fixed   = 4096 + (size_t)HW_ * sizeof(int);
    size_t atBytes = (size_t)(C_ / 4) * VPAD_ * 4 * sizeof(float);  // 2.49 MB
    float* AT4     = (float*)((char*)d_ws + fixed);
    float* BdT     = (float*)((char*)d_ws + fixed + atBytes);

    int jcap = 0;
    if (ws_size > fixed + atBytes) {
        size_t cols = (ws_size - fixed - atBytes) / ((size_t)C_ * sizeof(float));
        jcap = (int)(cols > 1024 ? 1024 : cols);
        jcap &= ~63;
    }

    hipLaunchKernelGGL(k_init, dim3(1), dim3(1), 0, stream, cnt);
    hipLaunchKernelGGL(k_main,
                       dim3(PF_BLOCKS_ + LOC_BLOCKS_ + FILL_BLOCKS_ +
                            TRANS_BLOCKS_),
                       dim3(256), 0, stream,
                       cls_feat, loc_feat, conf, pf_w, pf_b, vocab_w, vocab_b,
                       loc_w, loc_b, out, cnt, idxList, AT4, jcap);
    if (jcap > 0) {
        hipLaunchKernelGGL(k_gatherJ, dim3(512), dim3(256), 0, stream,
                           cls_feat, cnt, idxList, BdT, jcap);
        hipLaunchKernelGGL(k_gemm4, dim3(19, 64), dim3(256), 0, stream,
                           AT4, vocab_b, cnt, idxList, BdT, out, jcap);
    }
    hipLaunchKernelGGL(k_gemm_fallback, dim3((NC_ + 63) / 64, 8), dim3(256),
                       0, stream, cls_feat, vocab_w, vocab_b, cnt, idxList,
                       out, jcap);
}